// Round 13
// baseline (1140.858 us; speedup 1.0000x reference)
//
#include <hip/hip_runtime.h>
#include <stdint.h>

typedef __attribute__((ext_vector_type(8))) short short8;
typedef __attribute__((ext_vector_type(8))) unsigned short ushort8;
typedef __attribute__((ext_vector_type(4))) float f32x4;

#define MFMA(a,b,c) __builtin_amdgcn_mfma_f32_16x16x32_bf16((a),(b),(c),0,0,0)

__device__ __forceinline__ unsigned short f2bf(float f) {
  union { float f; unsigned u; } v; v.f = f;
  unsigned r = v.u + 0x7fffu + ((v.u >> 16) & 1u);
  return (unsigned short)(r >> 16);
}
__device__ __forceinline__ float bf2f(unsigned short s) {
  union { unsigned u; float f; } v; v.u = ((unsigned)s) << 16;
  return v.f;
}

// async global->LDS 16B: LDS dest is wave-uniform base + lane*16; global src per-lane
__device__ __forceinline__ void g2l16(const unsigned short* g, unsigned short* l) {
  __builtin_amdgcn_global_load_lds(
      (const __attribute__((address_space(1))) unsigned int*)(g),
      (__attribute__((address_space(3))) unsigned int*)(l), 16, 0, 0);
}

// V LDS swizzle: row c (128B = 32 banks), spread keys by high-and-low c bits.
// NOTE: XOR touches only bits >=3 of key, so groups of 4 adjacent keys stay adjacent.
__device__ __forceinline__ int vswz(int c, int key) {
  return key ^ ((((c >> 3) ^ c) & 7) << 3);
}

// ---------------- prep mega-kernel: 3 independent segments ------------------
// [0,27648): NCHW fp32 -> NHWC bf16 transpose (rgb->rgbN, fre->freN)
// [27648,28800): fold BN into qv/k weights (+ attn scale into q rows)
// [28800,29184): fold oc_w -> Wc[o][kq][c] bf16 + output-BN scale/shift
// NOTE: xpad border zeroing must NOT live here — freN aliases xpad and is
// still live until gemm1n completes (round-11 bug). It runs inside attn_all.
__launch_bounds__(256)
__global__ void prep_kernel(const float* __restrict__ rgb, const float* __restrict__ fre,
                            unsigned short* __restrict__ rgbN, unsigned short* __restrict__ freN,
                            const float* __restrict__ qv_w, const float* __restrict__ qv_b,
                            const float* __restrict__ k_w, const float* __restrict__ k_b,
                            const float* __restrict__ g, const float* __restrict__ be,
                            const float* __restrict__ mu, const float* __restrict__ var,
                            unsigned short* __restrict__ Wq, float* __restrict__ bq,
                            unsigned short* __restrict__ Wk, float* __restrict__ bk,
                            const float* __restrict__ oc_w, const float* __restrict__ oc_g,
                            const float* __restrict__ oc_b, const float* __restrict__ oc_m,
                            const float* __restrict__ oc_v,
                            unsigned short* __restrict__ Wc, float* __restrict__ s_oc,
                            float* __restrict__ t_oc) {
  __shared__ float smem[3456];   // union: nhwc tile (9216B) / fold_oc row (13824B) / partials
  int b = blockIdx.x;
  int t = threadIdx.x;
  if (b < 27648) {
    // ---- NHWC transpose, 64x64 tile ----
    unsigned short (*T)[72] = (unsigned short(*)[72])smem;
    int x = b % 576, y = (b / 576) % 6, z = b / 3456;
    int p0 = x * 64, c0 = y * 64, bb = z & 3;
    const float* S = (z < 4 ? rgb : fre) + (size_t)bb * 384 * 36864;
    unsigned short* D = (z < 4 ? rgbN : freN) + (size_t)bb * 36864 * 384;
    int pl = (t & 15) * 4;
    int r0 = t >> 4;
#pragma unroll
    for (int k = 0; k < 4; ++k) {
      int c = r0 + 16 * k;
      float4 v = *(const float4*)&S[(size_t)(c0 + c) * 36864 + p0 + pl];
      T[pl + 0][c] = f2bf(v.x); T[pl + 1][c] = f2bf(v.y);
      T[pl + 2][c] = f2bf(v.z); T[pl + 3][c] = f2bf(v.w);
    }
    __syncthreads();
    int row = t >> 2, ch = (t & 3) * 16;
    ushort8 a = *(const ushort8*)&T[row][ch];
    ushort8 bv = *(const ushort8*)&T[row][ch + 8];
    uint4* d = (uint4*)&D[(size_t)(p0 + row) * 384 + c0 + ch];
    d[0] = *(uint4*)&a; d[1] = *(uint4*)&bv;
  } else if (b < 28800) {
    // ---- fold_qvk: o in [0,768) -> qv row, [768,1152) -> k row ----
    int o = b - 27648;
    bool isq = o < 768;
    int oo = isq ? o : o - 768;
    const float* wrow = isq ? qv_w + (size_t)oo * 384 : k_w + (size_t)oo * 384;
    float mul = (isq && oo < 384) ? 0.08838834764831845f : 1.0f;  // 1/sqrt(128)
    float acc = 0.f;
    for (int c = t; c < 384; c += 256) {
      float sc = g[c] * rsqrtf(var[c] + 1e-5f);
      float sh = be[c] - mu[c] * sc;
      float w = wrow[c];
      acc += w * sh;
      unsigned short wb = f2bf(w * sc * mul);
      if (isq) Wq[(size_t)oo * 384 + c] = wb; else Wk[(size_t)oo * 384 + c] = wb;
    }
#pragma unroll
    for (int m2 = 1; m2 < 64; m2 <<= 1) acc += __shfl_xor(acc, m2);
    if ((t & 63) == 0) smem[t >> 6] = acc;
    __syncthreads();
    if (t == 0) {
      float b0 = isq ? qv_b[oo] : k_b[oo];
      float bias = (b0 + smem[0] + smem[1] + smem[2] + smem[3]) * mul;
      if (isq) bq[oo] = bias; else bk[oo] = bias;
    }
  } else {
    // ---- fold_oc: coalesced read via LDS, permute [c][kq]->[kq][c] ----
    int o = b - 28800;
    const float* src = oc_w + (size_t)o * 3456;
    for (int i = t; i < 3456; i += 256) smem[i] = src[i];
    if (t == 0) {
      float sc = oc_g[o] * rsqrtf(oc_v[o] + 1e-5f);
      s_oc[o] = sc;
      t_oc[o] = oc_b[o] - oc_m[o] * sc;
    }
    __syncthreads();
    unsigned short* dst = Wc + (size_t)o * 3456;
    for (int u = t; u < 3456; u += 256) {
      int kq = u / 384;
      int c = u - kq * 384;
      dst[u] = f2bf(smem[c * 9 + kq]);
    }
  }
}

// ---------------- fallback prep kernels (safe path) ------------------------
__global__ void fold_qvk_kernel(const float* __restrict__ qv_w, const float* __restrict__ qv_b,
                                const float* __restrict__ k_w, const float* __restrict__ k_b,
                                const float* __restrict__ g, const float* __restrict__ be,
                                const float* __restrict__ mu, const float* __restrict__ var,
                                unsigned short* __restrict__ Wq, float* __restrict__ bq,
                                unsigned short* __restrict__ Wk, float* __restrict__ bk) {
  int o = blockIdx.x;
  int t = threadIdx.x;           // 128
  bool isq = o < 768;
  int oo = isq ? o : o - 768;
  const float* wrow = isq ? qv_w + (size_t)oo * 384 : k_w + (size_t)oo * 384;
  float mul = (isq && oo < 384) ? 0.08838834764831845f : 1.0f;
  float acc = 0.f;
  for (int c = t; c < 384; c += 128) {
    float sc = g[c] * rsqrtf(var[c] + 1e-5f);
    float sh = be[c] - mu[c] * sc;
    float w = wrow[c];
    acc += w * sh;
    unsigned short wb = f2bf(w * sc * mul);
    if (isq) Wq[(size_t)oo * 384 + c] = wb; else Wk[(size_t)oo * 384 + c] = wb;
  }
#pragma unroll
  for (int m = 1; m < 64; m <<= 1) acc += __shfl_xor(acc, m);
  __shared__ float part[2];
  if ((t & 63) == 0) part[t >> 6] = acc;
  __syncthreads();
  if (t == 0) {
    float b0 = isq ? qv_b[oo] : k_b[oo];
    float bias = (b0 + part[0] + part[1]) * mul;
    if (isq) bq[oo] = bias; else bk[oo] = bias;
  }
}

__global__ void fold_oc_kernel(const float* __restrict__ oc_w,
                               const float* __restrict__ g, const float* __restrict__ be,
                               const float* __restrict__ mu, const float* __restrict__ var,
                               unsigned short* __restrict__ Wc, float* __restrict__ s_oc,
                               float* __restrict__ t_oc) {
  __shared__ float buf[3456];
  int o = blockIdx.x;
  int t = threadIdx.x;
  const float* src = oc_w + (size_t)o * 3456;
  for (int i = t; i < 3456; i += 256) buf[i] = src[i];
  if (t == 0) {
    float sc = g[o] * rsqrtf(var[o] + 1e-5f);
    s_oc[o] = sc;
    t_oc[o] = be[o] - mu[o] * sc;
  }
  __syncthreads();
  unsigned short* dst = Wc + (size_t)o * 3456;
  for (int u = t; u < 3456; u += 256) {
    int kq = u / 384;
    int c = u - kq * 384;
    dst[u] = f2bf(buf[c * 9 + kq]);
  }
}

// ------- 1x1 GEMM device body: 2-phase dbuf g2l16, 256p x 128o, BK=32 ------
__device__ __forceinline__ void gemm1n_body(const unsigned short* __restrict__ XN,
                                            const unsigned short* __restrict__ W,
                                            const float* __restrict__ bias,
                                            unsigned short* __restrict__ Out,
                                            int OW, int OT, int bi,
                                            unsigned short* Ws2, unsigned short* Xs2) {
  int ot = bi % OT;                                // ot innermost: X panel L2 reuse
  int pt = (bi / OT) % 144;
  int bb = bi / (OT * 144);
  int obase = ot * 128, pbase = pt * 256;
  int tid = threadIdx.x;
  int wv = tid >> 6, lane = tid & 63;
  int l15 = lane & 15, lg = lane >> 4;
  int wc = wv & 1, wr = wv >> 1;
  f32x4 acc[4][4];
#pragma unroll
  for (int i = 0; i < 4; ++i)
#pragma unroll
    for (int j = 0; j < 4; ++j) acc[i][j] = 0.f;
  int rl = lane >> 2;
  int csw = (((lane & 3) ^ ((lane >> 3) & 3)) << 3);
  const unsigned short* Ap = W + (size_t)(obase + 16 * wv + rl) * 384 + csw;
  const unsigned short* XbN = XN + (size_t)bb * 36864 * 384;
  const unsigned short* Bp0 = XbN + (size_t)(pbase + 32 * wv + rl) * 384 + csw;
  const unsigned short* Bp1 = Bp0 + (size_t)16 * 384;
  int colsw = ((lg ^ ((l15 >> 1) & 3)) << 3);
  unsigned short* WsW = Ws2 + (16 * wv) * 32;
  unsigned short* XsW0 = Xs2 + (32 * wv) * 32;
  unsigned short* XsW1 = Xs2 + (32 * wv + 16) * 32;
  const int WBUF = 128 * 32, XBUF = 256 * 32;
  g2l16(Ap, WsW); g2l16(Bp0, XsW0); g2l16(Bp1, XsW1);
  Ap += 32; Bp0 += 32; Bp1 += 32;
  for (int t = 0; t < 12; ++t) {
    int cur = t & 1, nxt = cur ^ 1;
    if (t < 11) {
      g2l16(Ap, WsW + nxt * WBUF);
      g2l16(Bp0, XsW0 + nxt * XBUF);
      g2l16(Bp1, XsW1 + nxt * XBUF);
      Ap += 32; Bp0 += 32; Bp1 += 32;
      asm volatile("s_waitcnt vmcnt(3)" ::: "memory");
    } else {
      asm volatile("s_waitcnt vmcnt(0)" ::: "memory");
    }
    __builtin_amdgcn_s_barrier();
    __builtin_amdgcn_sched_barrier(0);
    const unsigned short* Wt = Ws2 + cur * WBUF;
    const unsigned short* Xt = Xs2 + cur * XBUF;
    short8 af[4], bf[4];
#pragma unroll
    for (int f = 0; f < 4; ++f) af[f] = *(const short8*)&Xt[(wr * 64 + f * 16 + l15) * 32 + colsw];
#pragma unroll
    for (int f = 0; f < 4; ++f) bf[f] = *(const short8*)&Wt[(wc * 64 + f * 16 + l15) * 32 + colsw];
#pragma unroll
    for (int fm = 0; fm < 4; ++fm)
#pragma unroll
      for (int fn = 0; fn < 4; ++fn)
        acc[fm][fn] = MFMA(af[fm], bf[fn], acc[fm][fn]);
    __builtin_amdgcn_s_barrier();
    __builtin_amdgcn_sched_barrier(0);
  }
  unsigned short* Ob = Out + (size_t)bb * 36864 * OW;
#pragma unroll
  for (int fn = 0; fn < 4; ++fn) {
    int o = obase + wc * 64 + fn * 16 + l15;
    float bsv = bias[o];
#pragma unroll
    for (int fm = 0; fm < 4; ++fm) {
#pragma unroll
      for (int r = 0; r < 4; ++r) {
        int p = pbase + wr * 64 + fm * 16 + lg * 4 + r;
        Ob[(size_t)p * OW + o] = f2bf(acc[fm][fn][r] + bsv);
      }
    }
  }
}

// merged: blocks [0,3456) = qv GEMM, [3456,5184) = k GEMM
__launch_bounds__(512)
__global__ void gemm1n_all_kernel(const unsigned short* __restrict__ rgbN,
                                  const unsigned short* __restrict__ freN,
                                  const unsigned short* __restrict__ Wq, const float* __restrict__ bq,
                                  const unsigned short* __restrict__ Wk, const float* __restrict__ bk,
                                  unsigned short* __restrict__ qvbuf, unsigned short* __restrict__ kbuf) {
  __shared__ unsigned short Ws2[2 * 128 * 32];
  __shared__ unsigned short Xs2[2 * 256 * 32];
  int bid = blockIdx.x;
  if (bid < 3456) {
    int bi = (bid & 7) * 432 + (bid >> 3);   // XCD-contiguous within segment
    gemm1n_body(rgbN, Wq, bq, qvbuf, 768, 6, bi, Ws2, Xs2);
  } else {
    int idx = bid - 3456;
    int bi = (idx & 7) * 216 + (idx >> 3);
    gemm1n_body(freN, Wk, bk, kbuf, 384, 3, bi, Ws2, Xs2);
  }
}

// ---------------- GEMM-1 fallback (fp32 NCHW input, round-1 path) ----------
__launch_bounds__(256)
__global__ void gemm1_kernel(const float* __restrict__ X, const unsigned short* __restrict__ W,
                             const float* __restrict__ bias, unsigned short* __restrict__ Out,
                             int OW, int OT) {
  int bi = blockIdx.x;
  int ot = bi % OT;
  int pt = (bi / OT) % 288;
  int bb = bi / (OT * 288);
  int obase = ot * 128, pbase = pt * 128;
  __shared__ unsigned short As[128 * 40];
  __shared__ unsigned short Bs[128 * 40];
  int tid = threadIdx.x;
  int wv = tid >> 6, lane = tid & 63;
  int l15 = lane & 15, lg = lane >> 4;
  int pw = (wv >> 1) * 64, ow = (wv & 1) * 64;
  f32x4 acc[4][4];
#pragma unroll
  for (int i = 0; i < 4; ++i)
#pragma unroll
    for (int j = 0; j < 4; ++j) acc[i][j] = 0.f;
  const float* Xb = X + (size_t)bb * 384 * 36864;
  int arow = tid >> 1, ahalf = tid & 1;
  int bp = tid & 127, bcg0 = tid >> 7;
  for (int ks = 0; ks < 12; ++ks) {
    int c0 = ks * 32;
    __syncthreads();
    {
      const uint4* s4 = (const uint4*)(W + (size_t)(obase + arow) * 384 + c0 + ahalf * 16);
      uint4 a0 = s4[0], a1 = s4[1];
      uint4* d = (uint4*)&As[arow * 40 + ahalf * 16];
      d[0] = a0; d[1] = a1;
    }
    {
#pragma unroll
      for (int q = 0; q < 2; ++q) {
        int cg = bcg0 + q * 2;
        int cc = c0 + cg * 8;
        const float* src = Xb + (size_t)cc * 36864 + pbase + bp;
        ushort8 t8;
#pragma unroll
        for (int j = 0; j < 8; ++j) t8[j] = f2bf(src[(size_t)j * 36864]);
        *(ushort8*)&Bs[bp * 40 + cg * 8] = t8;
      }
    }
    __syncthreads();
    short8 af[4], bf[4];
#pragma unroll
    for (int f = 0; f < 4; ++f) af[f] = *(const short8*)&Bs[(pw + f * 16 + l15) * 40 + lg * 8];
#pragma unroll
    for (int f = 0; f < 4; ++f) bf[f] = *(const short8*)&As[(ow + f * 16 + l15) * 40 + lg * 8];
#pragma unroll
    for (int fm = 0; fm < 4; ++fm)
#pragma unroll
      for (int fn = 0; fn < 4; ++fn)
        acc[fm][fn] = MFMA(af[fm], bf[fn], acc[fm][fn]);
  }
  unsigned short* Ob = Out + (size_t)bb * 36864 * OW;
#pragma unroll
  for (int fn = 0; fn < 4; ++fn) {
    int o = obase + ow + fn * 16 + l15;
    float bsv = bias[o];
#pragma unroll
    for (int fm = 0; fm < 4; ++fm) {
#pragma unroll
      for (int r = 0; r < 4; ++r) {
        int p = pbase + pw + fm * 16 + lg * 4 + r;
        Ob[(size_t)p * OW + o] = f2bf(acc[fm][fn][r] + bsv);
      }
    }
  }
}

// ---------------- windowed attention device body, MODE 0/1/2 ---------------
// T14 async-STAGE: K/V global->reg loads issued one KV-tile ahead (hide HBM
// latency under previous tile's QK/softmax/PV); reg->LDS writes after the
// consumer barrier. +32 VGPR through compute; packing/swizzles unchanged.
template <int MODE>
__device__ __forceinline__ void attn_body(int bi, const unsigned short* qv, const unsigned short* kx,
                                          const float* __restrict__ rgb,
                                          const unsigned short* __restrict__ rgbn,
                                          unsigned short* xout, int padded,
                                          unsigned short* Qs, unsigned short* Ks,
                                          unsigned short* Vst, unsigned short* Ps) {
  constexpr int GB = MODE * 128;
  constexpr int NKV = (MODE == 2) ? 4 : 1;
  constexpr int NKF = (MODE == 0) ? 1 : 4;
  int bb = bi / 576;
  int r5 = bi % 576;
  int tid = threadIdx.x;
  int wv = tid >> 6, lane = tid & 63;
  int l15 = lane & 15, lg = lane >> 4;

  int h0, w0, qtb;
  if (MODE == 0) { int wy = r5 / 12; int wxb = (r5 % 12) * 4; h0 = wy * 4; w0 = wxb * 4; qtb = 0; }
  else if (MODE == 1) { int wy = r5 / 24; int wx = r5 % 24; h0 = wy * 8; w0 = wx * 8; qtb = 0; }
  else { int win = r5 >> 2; int qt = r5 & 3; int wy = win / 12; int wx = win % 12; h0 = wy * 16; w0 = wx * 16; qtb = qt * 64; }

  auto tok2p = [&](int t) -> int {
    if (MODE == 0) { int lw = t >> 4, tt = t & 15; return (h0 + (tt >> 2)) * 192 + w0 + lw * 4 + (tt & 3); }
    else if (MODE == 1) { return (h0 + (t >> 3)) * 192 + w0 + (t & 7); }
    else { return (h0 + (t >> 4)) * 192 + w0 + (t & 15); }
  };

  const unsigned short* qvB = qv + (size_t)bb * 36864 * 768;
  const unsigned short* kB = kx + (size_t)bb * 36864 * 384;

  // stage Q (64 tokens x 128 c)
  for (int ch = tid; ch < 1024; ch += 256) {
    int tok = ch >> 4, c8 = (ch & 15) << 3;
    int p = tok2p(qtb + tok);
    uint4 v = *(const uint4*)(qvB + (size_t)p * 768 + GB + c8);
    *(uint4*)&Qs[tok * 128 + (c8 ^ ((tok & 7) << 3))] = v;
  }
  __syncthreads();
  short8 qf[4];
  {
    int qrow = wv * 16 + l15;
#pragma unroll
    for (int cs = 0; cs < 4; ++cs)
      qf[cs] = *(const short8*)&Qs[qrow * 128 + ((cs * 32 + lg * 8) ^ ((qrow & 7) << 3))];
  }

  float m[4], s[4];
#pragma unroll
  for (int r = 0; r < 4; ++r) { m[r] = -1e30f; s[r] = 0.f; }
  f32x4 oacc[8];
#pragma unroll
  for (int i = 0; i < 8; ++i) oacc[i] = 0.f;

  // T14 staging state
  uint4 kreg[4];
  ushort8 vreg[4];
  int kc8 = (tid & 15) << 3;          // chunk col for both K and V staging
  int ktok0 = tid >> 4;               // K: tokens ktok0 + 16*i
  int vk4 = (tid >> 4) << 2;          // V: keys vk4..vk4+3
  auto LOADKV = [&](int kt) {
#pragma unroll
    for (int i = 0; i < 4; ++i)
      kreg[i] = *(const uint4*)(kB + (size_t)tok2p(kt * 64 + ktok0 + 16 * i) * 384 + GB + kc8);
#pragma unroll
    for (int j = 0; j < 4; ++j)
      vreg[j] = *(const ushort8*)(qvB + (size_t)tok2p(kt * 64 + vk4 + j) * 768 + 384 + GB + kc8);
  };
  LOADKV(0);

  for (int kt = 0; kt < NKV; ++kt) {
    __syncthreads();  // previous tile consumed by all waves
    // write staged K regs -> LDS (xor-swizzled rows)
#pragma unroll
    for (int i = 0; i < 4; ++i) {
      int tok = ktok0 + 16 * i;
      *(uint4*)&Ks[tok * 128 + (kc8 ^ ((tok & 7) << 3))] = kreg[i];
    }
    // write staged V regs -> LDS (transposed, packed pairs, vswz)
#pragma unroll
    for (int j = 0; j < 8; ++j) {
      int c = kc8 + j;
      uint2 w;
      w.x = (unsigned)vreg[0][j] | ((unsigned)vreg[1][j] << 16);
      w.y = (unsigned)vreg[2][j] | ((unsigned)vreg[3][j] << 16);
      *(uint2*)&Vst[c * 64 + vswz(c, vk4)] = w;
    }
    if (kt + 1 < NKV) LOADKV(kt + 1);  // issue next tile's loads; hide under compute
    __syncthreads();

    f32x4 sc[NKF];
#pragma unroll
    for (int kfi = 0; kfi < NKF; ++kfi) {
      int kf = (MODE == 0) ? wv : kfi;
      int krow = kf * 16 + l15;
      f32x4 a; a = 0.f;
#pragma unroll
      for (int cs = 0; cs < 4; ++cs) {
        short8 kfr = *(const short8*)&Ks[krow * 128 + ((cs * 32 + lg * 8) ^ ((krow & 7) << 3))];
        a = MFMA(qf[cs], kfr, a);
      }
      sc[kfi] = a;
    }

    unsigned short* Pw = Ps + wv * (16 * 72);
    float pr[4][NKF];
#pragma unroll
    for (int r = 0; r < 4; ++r) {
      float mx = -1e30f;
#pragma unroll
      for (int kfi = 0; kfi < NKF; ++kfi) mx = fmaxf(mx, sc[kfi][r]);
#pragma unroll
      for (int d = 1; d < 16; d <<= 1) mx = fmaxf(mx, __shfl_xor(mx, d));
      float mn = fmaxf(m[r], mx);
      float f = __expf(m[r] - mn);
      float ls = 0.f;
#pragma unroll
      for (int kfi = 0; kfi < NKF; ++kfi) { float e = __expf(sc[kfi][r] - mn); pr[r][kfi] = e; ls += e; }
#pragma unroll
      for (int d = 1; d < 16; d <<= 1) ls += __shfl_xor(ls, d);
      s[r] = s[r] * f + ls;
      m[r] = mn;
#pragma unroll
      for (int ct = 0; ct < 8; ++ct) oacc[ct][r] *= f;
    }
#pragma unroll
    for (int r = 0; r < 4; ++r) {
      int prow = lg * 4 + r;
#pragma unroll
      for (int kfi = 0; kfi < NKF; ++kfi) {
        int pcol = (MODE == 0) ? l15 : kfi * 16 + l15;
        Pw[prow * 72 + pcol] = f2bf(pr[r][kfi]);
      }
      if (MODE == 0) Pw[prow * 72 + 16 + l15] = 0;
    }
    constexpr int nks = (MODE == 0) ? 1 : 2;
#pragma unroll
    for (int ks = 0; ks < nks; ++ks) {
      short8 pf = *(const short8*)&Pw[l15 * 72 + ks * 32 + lg * 8];
#pragma unroll
      for (int ct = 0; ct < 8; ++ct) {
        int c = ct * 16 + l15;
        short8 vf;
        if (MODE == 0) {
          if (lg < 2) vf = *(const short8*)&Vst[c * 64 + vswz(c, wv * 16 + lg * 8)];
          else vf = 0;
        } else {
          vf = *(const short8*)&Vst[c * 64 + vswz(c, ks * 32 + lg * 8)];
        }
        oacc[ct] = MFMA(pf, vf, oacc[ct]);
      }
    }
  }

  // epilogue: divide by sum, add residual, store x (bf16)
  const float* rgbB = rgb + (size_t)bb * 384 * 36864;
  const unsigned short* rgbNB = rgbn + (size_t)bb * 36864 * 384;
  unsigned short* xB = padded ? xout + (size_t)bb * 37636 * 384
                              : xout + (size_t)bb * 36864 * 768;
#pragma unroll
  for (int r = 0; r < 4; ++r) {
    int q64 = wv * 16 + lg * 4 + r;
    int p = tok2p(qtb + q64);
    float inv = 1.0f / s[r];
    size_t rowoff;
    if (padded) {
      int h = p / 192, w = p % 192;
      rowoff = (size_t)((h + 1) * 194 + (w + 1)) * 384;
    } else {
      rowoff = (size_t)p * 768;
    }
#pragma unroll
    for (int ct = 0; ct < 8; ++ct) {
      int c = GB + ct * 16 + l15;
      float res = padded ? bf2f(rgbNB[(size_t)p * 384 + c]) : rgbB[(size_t)c * 36864 + p];
      float val = oacc[ct][r] * inv + res;
      xB[rowoff + c] = f2bf(val);
    }
  }
}

// merged: segments of 2304 per mode (XCD-contiguous remap within segment).
// Blocks [6912,7684) zero the xpad border — safe here because freN (aliasing
// xpad) is dead after gemm1n, and border rows are disjoint from attn's writes.
__launch_bounds__(256)
__global__ void attn_all_kernel(const unsigned short* qv, const unsigned short* kx,
                                const float* __restrict__ rgb, const unsigned short* __restrict__ rgbn,
                                unsigned short* xout, int padded) {
  __shared__ unsigned short Qs[64 * 128];
  __shared__ unsigned short Ks[64 * 128];
  __shared__ unsigned short Vst[128 * 64];
  __shared__ unsigned short Ps[4 * 16 * 72];
  int bid = blockIdx.x;
  if (bid >= 6912) {
    if (!padded) return;
    int i = bid - 6912;           // 772 border rows
    int t = threadIdx.x;
    int h, w;
    if (i < 194) { h = 0; w = i; }
    else if (i < 388) { h = 193; w = i - 194; }
    else if (i < 580) { w = 0; h = i - 388 + 1; }
    else { w = 193; h = i - 580 + 1; }
    if (t < 192) {
      int bb = t / 48, col = t % 48;
      uint4 z4 = {0, 0, 0, 0};
      uint4* row = (uint4*)(xout + ((size_t)bb * 37636 + h * 194 + w) * 384);
      row[col] = z4;
    }
    return;
  }
  int seg = (bid < 2304) ? 0 : ((bid < 4608) ? 1 : 2);
  int idx = bid - seg * 2304;
  int bi = (idx & 7) * 288 + (idx >> 3);
  if (seg == 0)      attn_body<0>(bi, qv, kx, rgb, rgbn, xout, padded, Qs, Ks, Vst, Ps);
  else if (seg == 1) attn_body<1>(bi, qv, kx, rgb, rgbn, xout, padded, Qs, Ks, Vst, Ps);
  else               attn_body<2>(bi, qv, kx, rgb, rgbn, xout, padded, Qs, Ks, Vst, Ps);
}

// ------ 3x3 conv: 2-phase double-buffered g2l16, 128o x 256p, BK=32 --------
// (verified round-5/8 kernel, 453us / MfmaUtil 39% / 0 bank conflicts)
__launch_bounds__(512)
__global__ void conv3d_kernel(const unsigned short* __restrict__ Xp,  // [b][37636][384] zero-padded
                              const unsigned short* __restrict__ Wc,
                              const float* __restrict__ s_oc, const float* __restrict__ t_oc,
                              float* __restrict__ Out) {
  // XCD-contiguous remap, ot innermost (X panel reused by 3 consecutive blocks)
  int bid = blockIdx.x;
  int bi = (bid & 7) * 216 + (bid >> 3);
  int ot = bi % 3;
  int pt = (bi / 3) % 144;
  int bb = bi / 432;
  int obase = ot * 128, pbase = pt * 256;
  __shared__ unsigned short Ws2[2][128 * 32];
  __shared__ unsigned short Xs2[2][256 * 32];
  int tid = threadIdx.x;
  int wv = tid >> 6, lane = tid & 63;
  int l15 = lane & 15, lg = lane >> 4;
  int wc = wv & 1, wr = wv >> 1;
  f32x4 acc[4][4];
#pragma unroll
  for (int i = 0; i < 4; ++i)
#pragma unroll
    for (int j = 0; j < 4; ++j) acc[i][j] = 0.f;
  int rl = lane >> 2;
  int csw = (((lane & 3) ^ ((lane >> 3) & 3)) << 3);
  const unsigned short* Ap = Wc + (size_t)(obase + 16 * wv + rl) * 3456 + csw;
  int p0 = pbase + 32 * wv + rl;
  int p1 = p0 + 16;
  const unsigned short* Xb = Xp + (size_t)bb * 37636 * 384;
  const unsigned short* Bp0 = Xb + (size_t)((p0 / 192 + 1) * 194 + (p0 % 192 + 1) - 195) * 384 + csw;
  const unsigned short* Bp1 = Xb + (size_t)((p1 / 192 + 1) * 194 + (p1 % 192 + 1) - 195) * 384 + csw;
  int colsw = ((lg ^ ((l15 >> 1) & 3)) << 3);
  unsigned short* WsW = &Ws2[0][(16 * wv) * 32];
  unsigned short* XsW0 = &Xs2[0][(32 * wv) * 32];
  unsigned short* XsW1 = &Xs2[0][(32 * wv + 16) * 32];
  const int WBUF = 128 * 32, XBUF = 256 * 32;
  g2l16(Ap, WsW); g2l16(Bp0, XsW0); g2l16(Bp1, XsW1);
  Ap += 32; Bp0 += 32; Bp1 += 32;
  for (int t = 0; t < 108; ++t) {
    int cur = t & 1, nxt = cur ^ 1;
    if (t < 107) {
      g2l16(Ap, WsW + nxt * WBUF);
      g2l16(Bp0, XsW0 + nxt * XBUF);
      g2l16(Bp1, XsW1 + nxt * XBUF);
      Ap += 32; Bp0 += 32; Bp1 += 32;
      if (t == 34 || t == 70) { Bp0 += 73344; Bp1 += 73344; }
      asm volatile("s_waitcnt vmcnt(3)" ::: "memory");
    } else {
      asm volatile("s_waitcnt vmcnt(0)" ::: "memory");
    }
    __builtin_amdgcn_s_barrier();
    __builtin_amdgcn_sched_barrier(0);
    const unsigned short* Wt = &Ws2[cur][0];
    const unsigned short* Xt = &Xs2[cur][0];
    short8 af[4], bf2[4];
#pragma unroll
    for (int f = 0; f < 4; ++f) af[f] = *(const short8*)&Wt[(wc * 64 + f * 16 + l15) * 32 + colsw];
#pragma unroll
    for (int f = 0; f < 4; ++f) bf2[f] = *(const short8*)&Xt[(wr * 64 + f * 16 + l15) * 32 + colsw];
#pragma unroll
    for (int fm = 0; fm < 4; ++fm)
#pragma unroll
      for (int fn = 0; fn < 4; ++fn)
        acc[fm][fn] = MFMA(af[fm], bf2[fn], acc[fm][fn]);
    __builtin_amdgcn_s_barrier();
    __builtin_amdgcn_sched_barrier(0);
  }
  float* Ob = Out + (size_t)bb * 384 * 36864;
#pragma unroll
  for (int fm = 0; fm < 4; ++fm) {
#pragma unroll
    for (int r = 0; r < 4; ++r) {
      int o = obase + wc * 64 + fm * 16 + lg * 4 + r;
      float sv = s_oc[o], tv = t_oc[o];
#pragma unroll
      for (int fn = 0; fn < 4; ++fn) {
        int p = pbase + wr * 64 + fn * 16 + l15;
        float y = acc[fm][fn][r] * sv + tv;
        Ob[(size_t)o * 36864 + p] = (y >= 0.f) ? y : 0.2f * y;
      }
    }
  }
}

// ---------------- fallback 3x3 conv (bounds-checked, no padding) -----------
__launch_bounds__(256)
__global__ void conv3_kernel(const unsigned short* __restrict__ X,
                             const unsigned short* __restrict__ Wc,
                             const float* __restrict__ s_oc, const float* __restrict__ t_oc,
                             float* __restrict__ Out) {
  int bi = blockIdx.x;
  int pt = bi % 288;
  int ot = (bi / 288) % 3;
  int bb = bi / 864;
  int obase = ot * 128, pbase = pt * 128;
  __shared__ unsigned short As[128 * 40];
  __shared__ unsigned short Bs[128 * 40];
  int tid = threadIdx.x;
  int wv = tid >> 6, lane = tid & 63;
  int l15 = lane & 15, lg = lane >> 4;
  int ow = (wv & 1) * 64, pw = (wv >> 1) * 64;
  f32x4 acc[4][4];
#pragma unroll
  for (int i = 0; i < 4; ++i)
#pragma unroll
    for (int j = 0; j < 4; ++j) acc[i][j] = 0.f;
  int arow = tid >> 1, ahalf = tid & 1;
  int sp = pbase + arow;
  int sh = sp / 192, sw = sp % 192;
  const unsigned short* Xb = X + (size_t)bb * 36864 * 768;
  for (int ksi = 0; ksi < 108; ++ksi) {
    int kq = ksi / 12;
    int c0 = (ksi % 12) * 32;
    int dh = kq / 3 - 1, dw = kq % 3 - 1;
    __syncthreads();
    {
      const uint4* s4 = (const uint4*)(Wc + (size_t)(obase + arow) * 3456 + kq * 384 + c0 + ahalf * 16);
      uint4 a0 = s4[0], a1 = s4[1];
      uint4* d = (uint4*)&As[arow * 40 + ahalf * 16];
      d[0] = a0; d[1] = a1;
    }
    {
      int hh = sh + dh, ww2 = sw + dw;
      uint4 b0 = {0, 0, 0, 0}, b1 = {0, 0, 0, 0};
      if ((unsigned)hh < 192u && (unsigned)ww2 < 192u) {
        const uint4* s4 = (const uint4*)(Xb + (size_t)(hh * 192 + ww2) * 768 + c0 + ahalf * 16);
        b0 = s4[0]; b1 = s4[1];
      }
      uint4* d = (uint4*)&Bs[arow * 40 + ahalf * 16];
      d[0] = b0; d[1] = b1;
    }
    __syncthreads();
    short8 af[4], bf2[4];
#pragma unroll
    for (int f = 0; f < 4; ++f) af[f] = *(const short8*)&As[(ow + f * 16 + l15) * 40 + lg * 8];
#pragma unroll
    for (int f = 0; f < 4; ++f) bf2[f] = *(const short8*)&Bs[(pw + f * 16 + l15) * 40 + lg * 8];
#pragma unroll
    for (int fm = 0; fm < 4; ++fm)
#pragma unroll
      for (int fn = 0; fn < 4; ++fn)
        acc[fm][fn] = MFMA(af[fm], bf2[fn], acc[fm][fn]);
  }
  float* Ob = Out + (size_t)bb * 384 * 36864;
#pragma unroll
  for (int fm = 0; fm < 4; ++fm) {
#pragma unroll
    for (int r = 0; r < 4; ++r) {
      int o = obase + ow + fm * 16 + lg * 4 + r;
      float sv = s_oc[o], tv = t_oc[o];
#pragma unroll
      for (int fn = 0; fn < 4; ++fn) {
        int p = pbase + pw + fn * 16 + l15;
        float y = acc[fm][fn][r] * sv + tv;
        Ob[(size_t)o * 36864 + p] = (y >= 0.f) ? y : 0.2f * y;
      }
    }
  }
}

// ---------------- launch ----------------
extern "C" void kernel_launch(void* const* d_in, const int* in_sizes, int n_in,
                              void* d_out, int out_size, void* d_ws, size_t ws_size,
                              hipStream_t stream) {
  const float* rgb  = (const float*)d_in[0];
  const float* fre  = (const float*)d_in[1];
  const float* ng   = (const float*)d_in[2];
  const float* nb   = (const float*)d_in[3];
  const float* nm   = (const float*)d_in[4];
  const float* nv   = (const float*)d_in[5];
  const float* qv_w = (const float*)d_in[6];
  const float* qv_b = (const float*)d_in[7];
  const float* k_w  = (const float*)d_in[8];
  const float* k_b  = (const float*)d_in[9];
  const float* oc_w = (const float*)d_in[10];
  const float* oc_g = (const float*)d_in[11];
  const float* oc_b = (const float*)d_in[12];
  const float* oc_m = (const float*)d_in[13];
  const float* oc_v = (const float*)d_in[14];

  char* ws = (char*)d_ws;
  const size_t QV_B   = 226492416;   // 147456*768*2
  const size_t K_B    = 113246208;   // 147456*384*2
  const size_t XPAD_B = 115617792;   // 4*37636*384*2  (also holds freN: 113246208 <= this)
  const size_t RGBN_B = 113246208;   // 4*36864*384*2
  size_t off = 0;
  unsigned short* qvbuf = (unsigned short*)(ws + off); off += QV_B;
  unsigned short* kbuf  = (unsigned short*)(ws + off); off += K_B;
  size_t dyn_off = off;
  unsigned short* xpad = (unsigned short*)(ws + dyn_off);          // also freN
  unsigned short* rgbN = (unsigned short*)(ws + dyn_off + XPAD_B);
  const size_t WEIGHTS_B = 589824 + 294912 + 2654208 + 3072 + 1536 + 1536 + 1536;
  bool fast = (ws_size >= dyn_off + XPAD_B + RGBN_B + WEIGHTS_B);
  if (fast) off += XPAD_B + RGBN_B;
  unsigned short* Wq = (unsigned short*)(ws + off); off += 589824;
  unsigned short* Wk = (unsigned short*)(ws + off); off += 294912;
  unsigned short* Wc = (unsigned short*)(ws + off); off += 2654208;
  float* bq  = (float*)(ws + off); off += 3072;
  float* bk  = (float*)(ws + off); off += 1536;
  float* soc = (float*)(ws + off); off += 1536;
  float* toc = (float*)(ws + off); off += 1536;
  float* out = (float*)d_out;

  if (fast) {
    unsigned short* freN = xpad;  // region reused: freN dead after gemm1n; border zeroed in attn_all
    prep_kernel<<<dim3(29184), dim3(256), 0, stream>>>(
        rgb, fre, rgbN, freN,
        qv_w, qv_b, k_w, k_b, ng, nb, nm, nv, Wq, bq, Wk, bk,
        oc_w, oc_g, oc_b, oc_m, oc_v, Wc, soc, toc);
    gemm1n_all_kernel<<<dim3(5184), dim3(512), 0, stream>>>(rgbN, freN, Wq, bq, Wk, bk, qvbuf, kbuf);
    attn_all_kernel<<<dim3(7684), dim3(256), 0, stream>>>(qvbuf, kbuf, rgb, rgbN, xpad, 1);
    conv3d_kernel<<<dim3(1728), dim3(512), 0, stream>>>(xpad, Wc, soc, toc, out);
  } else {
    fold_qvk_kernel<<<dim3(1152), dim3(128), 0, stream>>>(qv_w, qv_b, k_w, k_b, ng, nb, nm, nv, Wq, bq, Wk, bk);
    fold_oc_kernel<<<dim3(384), dim3(256), 0, stream>>>(oc_w, oc_g, oc_b, oc_m, oc_v, Wc, soc, toc);
    gemm1_kernel<<<dim3(4 * 288 * 6), dim3(256), 0, stream>>>(rgb, Wq, bq, qvbuf, 768, 6);
    gemm1_kernel<<<dim3(4 * 288 * 3), dim3(256), 0, stream>>>(fre, Wk, bk, kbuf, 384, 3);
    attn_all_kernel<<<dim3(6912), dim3(256), 0, stream>>>(qvbuf, kbuf, rgb, qvbuf, qvbuf, 0);
    conv3_kernel<<<dim3(4 * 3 * 288), dim3(256), 0, stream>>>(qvbuf, Wc, soc, toc, out);
  }
}

// Round 14
// 1134.478 us; speedup vs baseline: 1.0056x; 1.0056x over previous
//
#include <hip/hip_runtime.h>
#include <stdint.h>

typedef __attribute__((ext_vector_type(8))) short short8;
typedef __attribute__((ext_vector_type(8))) unsigned short ushort8;
typedef __attribute__((ext_vector_type(4))) float f32x4;

#define MFMA(a,b,c) __builtin_amdgcn_mfma_f32_16x16x32_bf16((a),(b),(c),0,0,0)

__device__ __forceinline__ unsigned short f2bf(float f) {
  union { float f; unsigned u; } v; v.f = f;
  unsigned r = v.u + 0x7fffu + ((v.u >> 16) & 1u);
  return (unsigned short)(r >> 16);
}
__device__ __forceinline__ float bf2f(unsigned short s) {
  union { unsigned u; float f; } v; v.u = ((unsigned)s) << 16;
  return v.f;
}

// async global->LDS 16B: LDS dest is wave-uniform base + lane*16; global src per-lane
__device__ __forceinline__ void g2l16(const unsigned short* g, unsigned short* l) {
  __builtin_amdgcn_global_load_lds(
      (const __attribute__((address_space(1))) unsigned int*)(g),
      (__attribute__((address_space(3))) unsigned int*)(l), 16, 0, 0);
}

// V LDS swizzle: row c (128B = 32 banks), spread keys by high-and-low c bits.
// NOTE: XOR touches only bits >=3 of key, so groups of 4 adjacent keys stay adjacent.
__device__ __forceinline__ int vswz(int c, int key) {
  return key ^ ((((c >> 3) ^ c) & 7) << 3);
}

// ---------------- prep mega-kernel: 3 independent segments ------------------
// [0,27648): NCHW fp32 -> NHWC bf16 transpose (rgb->rgbN, fre->freN)
// [27648,28800): fold BN into qv/k weights (+ attn scale into q rows)
// [28800,29184): fold oc_w -> Wc[o][kq][c] bf16 + output-BN scale/shift
// NOTE: xpad border zeroing must NOT live here — freN aliases xpad and is
// still live until gemm1n completes (round-11 bug). It runs inside attn_all.
__launch_bounds__(256)
__global__ void prep_kernel(const float* __restrict__ rgb, const float* __restrict__ fre,
                            unsigned short* __restrict__ rgbN, unsigned short* __restrict__ freN,
                            const float* __restrict__ qv_w, const float* __restrict__ qv_b,
                            const float* __restrict__ k_w, const float* __restrict__ k_b,
                            const float* __restrict__ g, const float* __restrict__ be,
                            const float* __restrict__ mu, const float* __restrict__ var,
                            unsigned short* __restrict__ Wq, float* __restrict__ bq,
                            unsigned short* __restrict__ Wk, float* __restrict__ bk,
                            const float* __restrict__ oc_w, const float* __restrict__ oc_g,
                            const float* __restrict__ oc_b, const float* __restrict__ oc_m,
                            const float* __restrict__ oc_v,
                            unsigned short* __restrict__ Wc, float* __restrict__ s_oc,
                            float* __restrict__ t_oc) {
  __shared__ float smem[3456];   // union: nhwc tile (9216B) / fold_oc row (13824B) / partials
  int b = blockIdx.x;
  int t = threadIdx.x;
  if (b < 27648) {
    // ---- NHWC transpose, 64x64 tile ----
    unsigned short (*T)[72] = (unsigned short(*)[72])smem;
    int x = b % 576, y = (b / 576) % 6, z = b / 3456;
    int p0 = x * 64, c0 = y * 64, bb = z & 3;
    const float* S = (z < 4 ? rgb : fre) + (size_t)bb * 384 * 36864;
    unsigned short* D = (z < 4 ? rgbN : freN) + (size_t)bb * 36864 * 384;
    int pl = (t & 15) * 4;
    int r0 = t >> 4;
#pragma unroll
    for (int k = 0; k < 4; ++k) {
      int c = r0 + 16 * k;
      float4 v = *(const float4*)&S[(size_t)(c0 + c) * 36864 + p0 + pl];
      T[pl + 0][c] = f2bf(v.x); T[pl + 1][c] = f2bf(v.y);
      T[pl + 2][c] = f2bf(v.z); T[pl + 3][c] = f2bf(v.w);
    }
    __syncthreads();
    int row = t >> 2, ch = (t & 3) * 16;
    ushort8 a = *(const ushort8*)&T[row][ch];
    ushort8 bv = *(const ushort8*)&T[row][ch + 8];
    uint4* d = (uint4*)&D[(size_t)(p0 + row) * 384 + c0 + ch];
    d[0] = *(uint4*)&a; d[1] = *(uint4*)&bv;
  } else if (b < 28800) {
    // ---- fold_qvk: o in [0,768) -> qv row, [768,1152) -> k row ----
    int o = b - 27648;
    bool isq = o < 768;
    int oo = isq ? o : o - 768;
    const float* wrow = isq ? qv_w + (size_t)oo * 384 : k_w + (size_t)oo * 384;
    float mul = (isq && oo < 384) ? 0.08838834764831845f : 1.0f;  // 1/sqrt(128)
    float acc = 0.f;
    for (int c = t; c < 384; c += 256) {
      float sc = g[c] * rsqrtf(var[c] + 1e-5f);
      float sh = be[c] - mu[c] * sc;
      float w = wrow[c];
      acc += w * sh;
      unsigned short wb = f2bf(w * sc * mul);
      if (isq) Wq[(size_t)oo * 384 + c] = wb; else Wk[(size_t)oo * 384 + c] = wb;
    }
#pragma unroll
    for (int m2 = 1; m2 < 64; m2 <<= 1) acc += __shfl_xor(acc, m2);
    if ((t & 63) == 0) smem[t >> 6] = acc;
    __syncthreads();
    if (t == 0) {
      float b0 = isq ? qv_b[oo] : k_b[oo];
      float bias = (b0 + smem[0] + smem[1] + smem[2] + smem[3]) * mul;
      if (isq) bq[oo] = bias; else bk[oo] = bias;
    }
  } else {
    // ---- fold_oc: coalesced read via LDS, permute [c][kq]->[kq][c] ----
    int o = b - 28800;
    const float* src = oc_w + (size_t)o * 3456;
    for (int i = t; i < 3456; i += 256) smem[i] = src[i];
    if (t == 0) {
      float sc = oc_g[o] * rsqrtf(oc_v[o] + 1e-5f);
      s_oc[o] = sc;
      t_oc[o] = oc_b[o] - oc_m[o] * sc;
    }
    __syncthreads();
    unsigned short* dst = Wc + (size_t)o * 3456;
    for (int u = t; u < 3456; u += 256) {
      int kq = u / 384;
      int c = u - kq * 384;
      dst[u] = f2bf(smem[c * 9 + kq]);
    }
  }
}

// ---------------- fallback prep kernels (safe path) ------------------------
__global__ void fold_qvk_kernel(const float* __restrict__ qv_w, const float* __restrict__ qv_b,
                                const float* __restrict__ k_w, const float* __restrict__ k_b,
                                const float* __restrict__ g, const float* __restrict__ be,
                                const float* __restrict__ mu, const float* __restrict__ var,
                                unsigned short* __restrict__ Wq, float* __restrict__ bq,
                                unsigned short* __restrict__ Wk, float* __restrict__ bk) {
  int o = blockIdx.x;
  int t = threadIdx.x;           // 128
  bool isq = o < 768;
  int oo = isq ? o : o - 768;
  const float* wrow = isq ? qv_w + (size_t)oo * 384 : k_w + (size_t)oo * 384;
  float mul = (isq && oo < 384) ? 0.08838834764831845f : 1.0f;
  float acc = 0.f;
  for (int c = t; c < 384; c += 128) {
    float sc = g[c] * rsqrtf(var[c] + 1e-5f);
    float sh = be[c] - mu[c] * sc;
    float w = wrow[c];
    acc += w * sh;
    unsigned short wb = f2bf(w * sc * mul);
    if (isq) Wq[(size_t)oo * 384 + c] = wb; else Wk[(size_t)oo * 384 + c] = wb;
  }
#pragma unroll
  for (int m = 1; m < 64; m <<= 1) acc += __shfl_xor(acc, m);
  __shared__ float part[2];
  if ((t & 63) == 0) part[t >> 6] = acc;
  __syncthreads();
  if (t == 0) {
    float b0 = isq ? qv_b[oo] : k_b[oo];
    float bias = (b0 + part[0] + part[1]) * mul;
    if (isq) bq[oo] = bias; else bk[oo] = bias;
  }
}

__global__ void fold_oc_kernel(const float* __restrict__ oc_w,
                               const float* __restrict__ g, const float* __restrict__ be,
                               const float* __restrict__ mu, const float* __restrict__ var,
                               unsigned short* __restrict__ Wc, float* __restrict__ s_oc,
                               float* __restrict__ t_oc) {
  __shared__ float buf[3456];
  int o = blockIdx.x;
  int t = threadIdx.x;
  const float* src = oc_w + (size_t)o * 3456;
  for (int i = t; i < 3456; i += 256) buf[i] = src[i];
  if (t == 0) {
    float sc = g[o] * rsqrtf(var[o] + 1e-5f);
    s_oc[o] = sc;
    t_oc[o] = be[o] - mu[o] * sc;
  }
  __syncthreads();
  unsigned short* dst = Wc + (size_t)o * 3456;
  for (int u = t; u < 3456; u += 256) {
    int kq = u / 384;
    int c = u - kq * 384;
    dst[u] = f2bf(buf[c * 9 + kq]);
  }
}

// ------- 1x1 GEMM device body: 2-phase dbuf g2l16, 256p x 128o, BK=32 ------
__device__ __forceinline__ void gemm1n_body(const unsigned short* __restrict__ XN,
                                            const unsigned short* __restrict__ W,
                                            const float* __restrict__ bias,
                                            unsigned short* __restrict__ Out,
                                            int OW, int OT, int bi,
                                            unsigned short* Ws2, unsigned short* Xs2) {
  int ot = bi % OT;                                // ot innermost: X panel L2 reuse
  int pt = (bi / OT) % 144;
  int bb = bi / (OT * 144);
  int obase = ot * 128, pbase = pt * 256;
  int tid = threadIdx.x;
  int wv = tid >> 6, lane = tid & 63;
  int l15 = lane & 15, lg = lane >> 4;
  int wc = wv & 1, wr = wv >> 1;
  f32x4 acc[4][4];
#pragma unroll
  for (int i = 0; i < 4; ++i)
#pragma unroll
    for (int j = 0; j < 4; ++j) acc[i][j] = 0.f;
  int rl = lane >> 2;
  int csw = (((lane & 3) ^ ((lane >> 3) & 3)) << 3);
  const unsigned short* Ap = W + (size_t)(obase + 16 * wv + rl) * 384 + csw;
  const unsigned short* XbN = XN + (size_t)bb * 36864 * 384;
  const unsigned short* Bp0 = XbN + (size_t)(pbase + 32 * wv + rl) * 384 + csw;
  const unsigned short* Bp1 = Bp0 + (size_t)16 * 384;
  int colsw = ((lg ^ ((l15 >> 1) & 3)) << 3);
  unsigned short* WsW = Ws2 + (16 * wv) * 32;
  unsigned short* XsW0 = Xs2 + (32 * wv) * 32;
  unsigned short* XsW1 = Xs2 + (32 * wv + 16) * 32;
  const int WBUF = 128 * 32, XBUF = 256 * 32;
  g2l16(Ap, WsW); g2l16(Bp0, XsW0); g2l16(Bp1, XsW1);
  Ap += 32; Bp0 += 32; Bp1 += 32;
  for (int t = 0; t < 12; ++t) {
    int cur = t & 1, nxt = cur ^ 1;
    if (t < 11) {
      g2l16(Ap, WsW + nxt * WBUF);
      g2l16(Bp0, XsW0 + nxt * XBUF);
      g2l16(Bp1, XsW1 + nxt * XBUF);
      Ap += 32; Bp0 += 32; Bp1 += 32;
      asm volatile("s_waitcnt vmcnt(3)" ::: "memory");
    } else {
      asm volatile("s_waitcnt vmcnt(0)" ::: "memory");
    }
    __builtin_amdgcn_s_barrier();
    __builtin_amdgcn_sched_barrier(0);
    const unsigned short* Wt = Ws2 + cur * WBUF;
    const unsigned short* Xt = Xs2 + cur * XBUF;
    short8 af[4], bf[4];
#pragma unroll
    for (int f = 0; f < 4; ++f) af[f] = *(const short8*)&Xt[(wr * 64 + f * 16 + l15) * 32 + colsw];
#pragma unroll
    for (int f = 0; f < 4; ++f) bf[f] = *(const short8*)&Wt[(wc * 64 + f * 16 + l15) * 32 + colsw];
#pragma unroll
    for (int fm = 0; fm < 4; ++fm)
#pragma unroll
      for (int fn = 0; fn < 4; ++fn)
        acc[fm][fn] = MFMA(af[fm], bf[fn], acc[fm][fn]);
    __builtin_amdgcn_s_barrier();
    __builtin_amdgcn_sched_barrier(0);
  }
  unsigned short* Ob = Out + (size_t)bb * 36864 * OW;
#pragma unroll
  for (int fn = 0; fn < 4; ++fn) {
    int o = obase + wc * 64 + fn * 16 + l15;
    float bsv = bias[o];
#pragma unroll
    for (int fm = 0; fm < 4; ++fm) {
#pragma unroll
      for (int r = 0; r < 4; ++r) {
        int p = pbase + wr * 64 + fm * 16 + lg * 4 + r;
        Ob[(size_t)p * OW + o] = f2bf(acc[fm][fn][r] + bsv);
      }
    }
  }
}

// merged: blocks [0,3456) = qv GEMM, [3456,5184) = k GEMM
__launch_bounds__(512)
__global__ void gemm1n_all_kernel(const unsigned short* __restrict__ rgbN,
                                  const unsigned short* __restrict__ freN,
                                  const unsigned short* __restrict__ Wq, const float* __restrict__ bq,
                                  const unsigned short* __restrict__ Wk, const float* __restrict__ bk,
                                  unsigned short* __restrict__ qvbuf, unsigned short* __restrict__ kbuf) {
  __shared__ unsigned short Ws2[2 * 128 * 32];
  __shared__ unsigned short Xs2[2 * 256 * 32];
  int bid = blockIdx.x;
  if (bid < 3456) {
    int bi = (bid & 7) * 432 + (bid >> 3);   // XCD-contiguous within segment
    gemm1n_body(rgbN, Wq, bq, qvbuf, 768, 6, bi, Ws2, Xs2);
  } else {
    int idx = bid - 3456;
    int bi = (idx & 7) * 216 + (idx >> 3);
    gemm1n_body(freN, Wk, bk, kbuf, 384, 3, bi, Ws2, Xs2);
  }
}

// ---------------- GEMM-1 fallback (fp32 NCHW input, round-1 path) ----------
__launch_bounds__(256)
__global__ void gemm1_kernel(const float* __restrict__ X, const unsigned short* __restrict__ W,
                             const float* __restrict__ bias, unsigned short* __restrict__ Out,
                             int OW, int OT) {
  int bi = blockIdx.x;
  int ot = bi % OT;
  int pt = (bi / OT) % 288;
  int bb = bi / (OT * 288);
  int obase = ot * 128, pbase = pt * 128;
  __shared__ unsigned short As[128 * 40];
  __shared__ unsigned short Bs[128 * 40];
  int tid = threadIdx.x;
  int wv = tid >> 6, lane = tid & 63;
  int l15 = lane & 15, lg = lane >> 4;
  int pw = (wv >> 1) * 64, ow = (wv & 1) * 64;
  f32x4 acc[4][4];
#pragma unroll
  for (int i = 0; i < 4; ++i)
#pragma unroll
    for (int j = 0; j < 4; ++j) acc[i][j] = 0.f;
  const float* Xb = X + (size_t)bb * 384 * 36864;
  int arow = tid >> 1, ahalf = tid & 1;
  int bp = tid & 127, bcg0 = tid >> 7;
  for (int ks = 0; ks < 12; ++ks) {
    int c0 = ks * 32;
    __syncthreads();
    {
      const uint4* s4 = (const uint4*)(W + (size_t)(obase + arow) * 384 + c0 + ahalf * 16);
      uint4 a0 = s4[0], a1 = s4[1];
      uint4* d = (uint4*)&As[arow * 40 + ahalf * 16];
      d[0] = a0; d[1] = a1;
    }
    {
#pragma unroll
      for (int q = 0; q < 2; ++q) {
        int cg = bcg0 + q * 2;
        int cc = c0 + cg * 8;
        const float* src = Xb + (size_t)cc * 36864 + pbase + bp;
        ushort8 t8;
#pragma unroll
        for (int j = 0; j < 8; ++j) t8[j] = f2bf(src[(size_t)j * 36864]);
        *(ushort8*)&Bs[bp * 40 + cg * 8] = t8;
      }
    }
    __syncthreads();
    short8 af[4], bf[4];
#pragma unroll
    for (int f = 0; f < 4; ++f) af[f] = *(const short8*)&Bs[(pw + f * 16 + l15) * 40 + lg * 8];
#pragma unroll
    for (int f = 0; f < 4; ++f) bf[f] = *(const short8*)&As[(ow + f * 16 + l15) * 40 + lg * 8];
#pragma unroll
    for (int fm = 0; fm < 4; ++fm)
#pragma unroll
      for (int fn = 0; fn < 4; ++fn)
        acc[fm][fn] = MFMA(af[fm], bf[fn], acc[fm][fn]);
  }
  unsigned short* Ob = Out + (size_t)bb * 36864 * OW;
#pragma unroll
  for (int fn = 0; fn < 4; ++fn) {
    int o = obase + ow + fn * 16 + l15;
    float bsv = bias[o];
#pragma unroll
    for (int fm = 0; fm < 4; ++fm) {
#pragma unroll
      for (int r = 0; r < 4; ++r) {
        int p = pbase + pw + fm * 16 + lg * 4 + r;
        Ob[(size_t)p * OW + o] = f2bf(acc[fm][fn][r] + bsv);
      }
    }
  }
}

// ---------------- windowed attention device body, MODE 0/1/2 ---------------
// (round-12 verified staging: loads between barriers; T14 reverted as null)
template <int MODE>
__device__ __forceinline__ void attn_body(int bi, const unsigned short* qv, const unsigned short* kx,
                                          const float* __restrict__ rgb,
                                          const unsigned short* __restrict__ rgbn,
                                          unsigned short* xout, int padded,
                                          unsigned short* Qs, unsigned short* Ks,
                                          unsigned short* Vst, unsigned short* Ps) {
  constexpr int GB = MODE * 128;
  constexpr int NKV = (MODE == 2) ? 4 : 1;
  constexpr int NKF = (MODE == 0) ? 1 : 4;
  int bb = bi / 576;
  int r5 = bi % 576;
  int tid = threadIdx.x;
  int wv = tid >> 6, lane = tid & 63;
  int l15 = lane & 15, lg = lane >> 4;

  int h0, w0, qtb;
  if (MODE == 0) { int wy = r5 / 12; int wxb = (r5 % 12) * 4; h0 = wy * 4; w0 = wxb * 4; qtb = 0; }
  else if (MODE == 1) { int wy = r5 / 24; int wx = r5 % 24; h0 = wy * 8; w0 = wx * 8; qtb = 0; }
  else { int win = r5 >> 2; int qt = r5 & 3; int wy = win / 12; int wx = win % 12; h0 = wy * 16; w0 = wx * 16; qtb = qt * 64; }

  auto tok2p = [&](int t) -> int {
    if (MODE == 0) { int lw = t >> 4, tt = t & 15; return (h0 + (tt >> 2)) * 192 + w0 + lw * 4 + (tt & 3); }
    else if (MODE == 1) { return (h0 + (t >> 3)) * 192 + w0 + (t & 7); }
    else { return (h0 + (t >> 4)) * 192 + w0 + (t & 15); }
  };

  const unsigned short* qvB = qv + (size_t)bb * 36864 * 768;
  const unsigned short* kB = kx + (size_t)bb * 36864 * 384;

  // stage Q (64 tokens x 128 c)
  for (int ch = tid; ch < 1024; ch += 256) {
    int tok = ch >> 4, c8 = (ch & 15) << 3;
    int p = tok2p(qtb + tok);
    uint4 v = *(const uint4*)(qvB + (size_t)p * 768 + GB + c8);
    *(uint4*)&Qs[tok * 128 + (c8 ^ ((tok & 7) << 3))] = v;
  }
  __syncthreads();
  short8 qf[4];
  {
    int qrow = wv * 16 + l15;
#pragma unroll
    for (int cs = 0; cs < 4; ++cs)
      qf[cs] = *(const short8*)&Qs[qrow * 128 + ((cs * 32 + lg * 8) ^ ((qrow & 7) << 3))];
  }

  float m[4], s[4];
#pragma unroll
  for (int r = 0; r < 4; ++r) { m[r] = -1e30f; s[r] = 0.f; }
  f32x4 oacc[8];
#pragma unroll
  for (int i = 0; i < 8; ++i) oacc[i] = 0.f;

  for (int kt = 0; kt < NKV; ++kt) {
    __syncthreads();
    for (int ch = tid; ch < 1024; ch += 256) {  // stage K tile
      int tok = ch >> 4, c8 = (ch & 15) << 3;
      int p = tok2p(kt * 64 + tok);
      uint4 v = *(const uint4*)(kB + (size_t)p * 384 + GB + c8);
      *(uint4*)&Ks[tok * 128 + (c8 ^ ((tok & 7) << 3))] = v;
    }
    {  // stage V tile (transposed): thread = (k4, c8) -> 4 keys x 8 c.
      int c8 = (tid & 15) << 3;
      int k4 = (tid >> 4) << 2;
      ushort8 v0 = *(const ushort8*)(qvB + (size_t)tok2p(kt * 64 + k4 + 0) * 768 + 384 + GB + c8);
      ushort8 v1 = *(const ushort8*)(qvB + (size_t)tok2p(kt * 64 + k4 + 1) * 768 + 384 + GB + c8);
      ushort8 v2 = *(const ushort8*)(qvB + (size_t)tok2p(kt * 64 + k4 + 2) * 768 + 384 + GB + c8);
      ushort8 v3 = *(const ushort8*)(qvB + (size_t)tok2p(kt * 64 + k4 + 3) * 768 + 384 + GB + c8);
#pragma unroll
      for (int j = 0; j < 8; ++j) {
        int c = c8 + j;
        uint2 w;
        w.x = (unsigned)v0[j] | ((unsigned)v1[j] << 16);
        w.y = (unsigned)v2[j] | ((unsigned)v3[j] << 16);
        *(uint2*)&Vst[c * 64 + vswz(c, k4)] = w;
      }
    }
    __syncthreads();

    f32x4 sc[NKF];
#pragma unroll
    for (int kfi = 0; kfi < NKF; ++kfi) {
      int kf = (MODE == 0) ? wv : kfi;
      int krow = kf * 16 + l15;
      f32x4 a; a = 0.f;
#pragma unroll
      for (int cs = 0; cs < 4; ++cs) {
        short8 kfr = *(const short8*)&Ks[krow * 128 + ((cs * 32 + lg * 8) ^ ((krow & 7) << 3))];
        a = MFMA(qf[cs], kfr, a);
      }
      sc[kfi] = a;
    }

    unsigned short* Pw = Ps + wv * (16 * 72);
    float pr[4][NKF];
#pragma unroll
    for (int r = 0; r < 4; ++r) {
      float mx = -1e30f;
#pragma unroll
      for (int kfi = 0; kfi < NKF; ++kfi) mx = fmaxf(mx, sc[kfi][r]);
#pragma unroll
      for (int d = 1; d < 16; d <<= 1) mx = fmaxf(mx, __shfl_xor(mx, d));
      float mn = fmaxf(m[r], mx);
      float f = __expf(m[r] - mn);
      float ls = 0.f;
#pragma unroll
      for (int kfi = 0; kfi < NKF; ++kfi) { float e = __expf(sc[kfi][r] - mn); pr[r][kfi] = e; ls += e; }
#pragma unroll
      for (int d = 1; d < 16; d <<= 1) ls += __shfl_xor(ls, d);
      s[r] = s[r] * f + ls;
      m[r] = mn;
#pragma unroll
      for (int ct = 0; ct < 8; ++ct) oacc[ct][r] *= f;
    }
#pragma unroll
    for (int r = 0; r < 4; ++r) {
      int prow = lg * 4 + r;
#pragma unroll
      for (int kfi = 0; kfi < NKF; ++kfi) {
        int pcol = (MODE == 0) ? l15 : kfi * 16 + l15;
        Pw[prow * 72 + pcol] = f2bf(pr[r][kfi]);
      }
      if (MODE == 0) Pw[prow * 72 + 16 + l15] = 0;
    }
    constexpr int nks = (MODE == 0) ? 1 : 2;
#pragma unroll
    for (int ks = 0; ks < nks; ++ks) {
      short8 pf = *(const short8*)&Pw[l15 * 72 + ks * 32 + lg * 8];
#pragma unroll
      for (int ct = 0; ct < 8; ++ct) {
        int c = ct * 16 + l15;
        short8 vf;
        if (MODE == 0) {
          if (lg < 2) vf = *(const short8*)&Vst[c * 64 + vswz(c, wv * 16 + lg * 8)];
          else vf = 0;
        } else {
          vf = *(const short8*)&Vst[c * 64 + vswz(c, ks * 32 + lg * 8)];
        }
        oacc[ct] = MFMA(pf, vf, oacc[ct]);
      }
    }
  }

  // epilogue: divide by sum, add residual, store x (bf16)
  const float* rgbB = rgb + (size_t)bb * 384 * 36864;
  const unsigned short* rgbNB = rgbn + (size_t)bb * 36864 * 384;
  unsigned short* xB = padded ? xout + (size_t)bb * 37636 * 384
                              : xout + (size_t)bb * 36864 * 768;
#pragma unroll
  for (int r = 0; r < 4; ++r) {
    int q64 = wv * 16 + lg * 4 + r;
    int p = tok2p(qtb + q64);
    float inv = 1.0f / s[r];
    size_t rowoff;
    if (padded) {
      int h = p / 192, w = p % 192;
      rowoff = (size_t)((h + 1) * 194 + (w + 1)) * 384;
    } else {
      rowoff = (size_t)p * 768;
    }
#pragma unroll
    for (int ct = 0; ct < 8; ++ct) {
      int c = GB + ct * 16 + l15;
      float res = padded ? bf2f(rgbNB[(size_t)p * 384 + c]) : rgbB[(size_t)c * 36864 + p];
      float val = oacc[ct][r] * inv + res;
      xB[rowoff + c] = f2bf(val);
    }
  }
}

// merged: segments of 2304 per mode (XCD-contiguous remap within segment).
// Blocks [6912,7684) zero the xpad border — safe here because freN (aliasing
// xpad) is dead after gemm1n, and border rows are disjoint from attn's writes.
__launch_bounds__(256)
__global__ void attn_all_kernel(const unsigned short* qv, const unsigned short* kx,
                                const float* __restrict__ rgb, const unsigned short* __restrict__ rgbn,
                                unsigned short* xout, int padded) {
  __shared__ unsigned short Qs[64 * 128];
  __shared__ unsigned short Ks[64 * 128];
  __shared__ unsigned short Vst[128 * 64];
  __shared__ unsigned short Ps[4 * 16 * 72];
  int bid = blockIdx.x;
  if (bid >= 6912) {
    if (!padded) return;
    int i = bid - 6912;           // 772 border rows
    int t = threadIdx.x;
    int h, w;
    if (i < 194) { h = 0; w = i; }
    else if (i < 388) { h = 193; w = i - 194; }
    else if (i < 580) { w = 0; h = i - 388 + 1; }
    else { w = 193; h = i - 580 + 1; }
    if (t < 192) {
      int bb = t / 48, col = t % 48;
      uint4 z4 = {0, 0, 0, 0};
      uint4* row = (uint4*)(xout + ((size_t)bb * 37636 + h * 194 + w) * 384);
      row[col] = z4;
    }
    return;
  }
  int seg = (bid < 2304) ? 0 : ((bid < 4608) ? 1 : 2);
  int idx = bid - seg * 2304;
  int bi = (idx & 7) * 288 + (idx >> 3);
  if (seg == 0)      attn_body<0>(bi, qv, kx, rgb, rgbn, xout, padded, Qs, Ks, Vst, Ps);
  else if (seg == 1) attn_body<1>(bi, qv, kx, rgb, rgbn, xout, padded, Qs, Ks, Vst, Ps);
  else               attn_body<2>(bi, qv, kx, rgb, rgbn, xout, padded, Qs, Ks, Vst, Ps);
}

// ------ 3x3 conv: 2-phase double-buffered g2l16, 128o x 256p, BK=32 --------
// (verified round-5/8 kernel, 453us / MfmaUtil 39% / 0 bank conflicts)
__launch_bounds__(512)
__global__ void conv3d_kernel(const unsigned short* __restrict__ Xp,  // [b][37636][384] zero-padded
                              const unsigned short* __restrict__ Wc,
                              const float* __restrict__ s_oc, const float* __restrict__ t_oc,
                              float* __restrict__ Out) {
  // XCD-contiguous remap, ot innermost (X panel reused by 3 consecutive blocks)
  int bid = blockIdx.x;
  int bi = (bid & 7) * 216 + (bid >> 3);
  int ot = bi % 3;
  int pt = (bi / 3) % 144;
  int bb = bi / 432;
  int obase = ot * 128, pbase = pt * 256;
  __shared__ unsigned short Ws2[2][128 * 32];
  __shared__ unsigned short Xs2[2][256 * 32];
  int tid = threadIdx.x;
  int wv = tid >> 6, lane = tid & 63;
  int l15 = lane & 15, lg = lane >> 4;
  int wc = wv & 1, wr = wv >> 1;
  f32x4 acc[4][4];
#pragma unroll
  for (int i = 0; i < 4; ++i)
#pragma unroll
    for (int j = 0; j < 4; ++j) acc[i][j] = 0.f;
  int rl = lane >> 2;
  int csw = (((lane & 3) ^ ((lane >> 3) & 3)) << 3);
  const unsigned short* Ap = Wc + (size_t)(obase + 16 * wv + rl) * 3456 + csw;
  int p0 = pbase + 32 * wv + rl;
  int p1 = p0 + 16;
  const unsigned short* Xb = Xp + (size_t)bb * 37636 * 384;
  const unsigned short* Bp0 = Xb + (size_t)((p0 / 192 + 1) * 194 + (p0 % 192 + 1) - 195) * 384 + csw;
  const unsigned short* Bp1 = Xb + (size_t)((p1 / 192 + 1) * 194 + (p1 % 192 + 1) - 195) * 384 + csw;
  int colsw = ((lg ^ ((l15 >> 1) & 3)) << 3);
  unsigned short* WsW = &Ws2[0][(16 * wv) * 32];
  unsigned short* XsW0 = &Xs2[0][(32 * wv) * 32];
  unsigned short* XsW1 = &Xs2[0][(32 * wv + 16) * 32];
  const int WBUF = 128 * 32, XBUF = 256 * 32;
  g2l16(Ap, WsW); g2l16(Bp0, XsW0); g2l16(Bp1, XsW1);
  Ap += 32; Bp0 += 32; Bp1 += 32;
  for (int t = 0; t < 108; ++t) {
    int cur = t & 1, nxt = cur ^ 1;
    if (t < 107) {
      g2l16(Ap, WsW + nxt * WBUF);
      g2l16(Bp0, XsW0 + nxt * XBUF);
      g2l16(Bp1, XsW1 + nxt * XBUF);
      Ap += 32; Bp0 += 32; Bp1 += 32;
      if (t == 34 || t == 70) { Bp0 += 73344; Bp1 += 73344; }
      asm volatile("s_waitcnt vmcnt(3)" ::: "memory");
    } else {
      asm volatile("s_waitcnt vmcnt(0)" ::: "memory");
    }
    __builtin_amdgcn_s_barrier();
    __builtin_amdgcn_sched_barrier(0);
    const unsigned short* Wt = &Ws2[cur][0];
    const unsigned short* Xt = &Xs2[cur][0];
    short8 af[4], bf2[4];
#pragma unroll
    for (int f = 0; f < 4; ++f) af[f] = *(const short8*)&Wt[(wc * 64 + f * 16 + l15) * 32 + colsw];
#pragma unroll
    for (int f = 0; f < 4; ++f) bf2[f] = *(const short8*)&Xt[(wr * 64 + f * 16 + l15) * 32 + colsw];
#pragma unroll
    for (int fm = 0; fm < 4; ++fm)
#pragma unroll
      for (int fn = 0; fn < 4; ++fn)
        acc[fm][fn] = MFMA(af[fm], bf2[fn], acc[fm][fn]);
    __builtin_amdgcn_s_barrier();
    __builtin_amdgcn_sched_barrier(0);
  }
  float* Ob = Out + (size_t)bb * 384 * 36864;
#pragma unroll
  for (int fm = 0; fm < 4; ++fm) {
#pragma unroll
    for (int r = 0; r < 4; ++r) {
      int o = obase + wc * 64 + fm * 16 + lg * 4 + r;
      float sv = s_oc[o], tv = t_oc[o];
#pragma unroll
      for (int fn = 0; fn < 4; ++fn) {
        int p = pbase + wr * 64 + fn * 16 + l15;
        float y = acc[fm][fn][r] * sv + tv;
        Ob[(size_t)o * 36864 + p] = (y >= 0.f) ? y : 0.2f * y;
      }
    }
  }
}

// ---------------- fallback 3x3 conv (bounds-checked, no padding) -----------
__launch_bounds__(256)
__global__ void conv3_kernel(const unsigned short* __restrict__ X,
                             const unsigned short* __restrict__ Wc,
                             const float* __restrict__ s_oc, const float* __restrict__ t_oc,
                             float* __restrict__ Out) {
  int bi = blockIdx.x;
  int pt = bi % 288;
  int ot = (bi / 288) % 3;
  int bb = bi / 864;
  int obase = ot * 128, pbase = pt * 128;
  __shared__ unsigned short As[128 * 40];
  __shared__ unsigned short Bs[128 * 40];
  int tid = threadIdx.x;
  int wv = tid >> 6, lane = tid & 63;
  int l15 = lane & 15, lg = lane >> 4;
  int ow = (wv & 1) * 64, pw = (wv >> 1) * 64;
  f32x4 acc[4][4];
#pragma unroll
  for (int i = 0; i < 4; ++i)
#pragma unroll
    for (int j = 0; j < 4; ++j) acc[i][j] = 0.f;
  int arow = tid >> 1, ahalf = tid & 1;
  int sp = pbase + arow;
  int sh = sp / 192, sw = sp % 192;
  const unsigned short* Xb = X + (size_t)bb * 36864 * 768;
  for (int ksi = 0; ksi < 108; ++ksi) {
    int kq = ksi / 12;
    int c0 = (ksi % 12) * 32;
    int dh = kq / 3 - 1, dw = kq % 3 - 1;
    __syncthreads();
    {
      const uint4* s4 = (const uint4*)(Wc + (size_t)(obase + arow) * 3456 + kq * 384 + c0 + ahalf * 16);
      uint4 a0 = s4[0], a1 = s4[1];
      uint4* d = (uint4*)&As[arow * 40 + ahalf * 16];
      d[0] = a0; d[1] = a1;
    }
    {
      int hh = sh + dh, ww2 = sw + dw;
      uint4 b0 = {0, 0, 0, 0}, b1 = {0, 0, 0, 0};
      if ((unsigned)hh < 192u && (unsigned)ww2 < 192u) {
        const uint4* s4 = (const uint4*)(Xb + (size_t)(hh * 192 + ww2) * 768 + c0 + ahalf * 16);
        b0 = s4[0]; b1 = s4[1];
      }
      uint4* d = (uint4*)&Bs[arow * 40 + ahalf * 16];
      d[0] = b0; d[1] = b1;
    }
    __syncthreads();
    short8 af[4], bf2[4];
#pragma unroll
    for (int f = 0; f < 4; ++f) af[f] = *(const short8*)&As[(ow + f * 16 + l15) * 40 + lg * 8];
#pragma unroll
    for (int f = 0; f < 4; ++f) bf2[f] = *(const short8*)&Bs[(pw + f * 16 + l15) * 40 + lg * 8];
#pragma unroll
    for (int fm = 0; fm < 4; ++fm)
#pragma unroll
      for (int fn = 0; fn < 4; ++fn)
        acc[fm][fn] = MFMA(af[fm], bf2[fn], acc[fm][fn]);
  }
  float* Ob = Out + (size_t)bb * 384 * 36864;
#pragma unroll
  for (int fm = 0; fm < 4; ++fm) {
#pragma unroll
    for (int r = 0; r < 4; ++r) {
      int o = obase + ow + fm * 16 + lg * 4 + r;
      float sv = s_oc[o], tv = t_oc[o];
#pragma unroll
      for (int fn = 0; fn < 4; ++fn) {
        int p = pbase + pw + fn * 16 + l15;
        float y = acc[fm][fn][r] * sv + tv;
        Ob[(size_t)o * 36864 + p] = (y >= 0.f) ? y : 0.2f * y;
      }
    }
  }
}

// ---------------- launch ----------------
extern "C" void kernel_launch(void* const* d_in, const int* in_sizes, int n_in,
                              void* d_out, int out_size, void* d_ws, size_t ws_size,
                              hipStream_t stream) {
  const float* rgb  = (const float*)d_in[0];
  const float* fre  = (const float*)d_in[1];
  const float* ng   = (const float*)d_in[2];
  const float* nb   = (const float*)d_in[3];
  const float* nm   = (const float*)d_in[4];
  const float* nv   = (const float*)d_in[5];
  const float* qv_w = (const float*)d_in[6];
  const float* qv_b = (const float*)d_in[7];
  const float* k_w  = (const float*)d_in[8];
  const float* k_b  = (const float*)d_in[9];
  const float* oc_w = (const float*)d_in[10];
  const float* oc_g = (const float*)d_in[11];
  const float* oc_b = (const float*)d_in[12];
  const float* oc_m = (const float*)d_in[13];
  const float* oc_v = (const float*)d_in[14];

  char* ws = (char*)d_ws;
  const size_t QV_B   = 226492416;   // 147456*768*2
  const size_t K_B    = 113246208;   // 147456*384*2
  const size_t XPAD_B = 115617792;   // 4*37636*384*2  (also holds freN: 113246208 <= this)
  const size_t RGBN_B = 113246208;   // 4*36864*384*2
  size_t off = 0;
  unsigned short* qvbuf = (unsigned short*)(ws + off); off += QV_B;
  unsigned short* kbuf  = (unsigned short*)(ws + off); off += K_B;
  size_t dyn_off = off;
  unsigned short* xpad = (unsigned short*)(ws + dyn_off);          // also freN
  unsigned short* rgbN = (unsigned short*)(ws + dyn_off + XPAD_B);
  const size_t WEIGHTS_B = 589824 + 294912 + 2654208 + 3072 + 1536 + 1536 + 1536;
  bool fast = (ws_size >= dyn_off + XPAD_B + RGBN_B + WEIGHTS_B);
  if (fast) off += XPAD_B + RGBN_B;
  unsigned short* Wq = (unsigned short*)(ws + off); off += 589824;
  unsigned short* Wk = (unsigned short*)(ws + off); off += 294912;
  unsigned short* Wc = (unsigned short*)(ws + off); off += 2654208;
  float* bq  = (float*)(ws + off); off += 3072;
  float* bk  = (float*)(ws + off); off += 1536;
  float* soc = (float*)(ws + off); off += 1536;
  float* toc = (float*)(ws + off); off += 1536;
  float* out = (float*)d_out;

  if (fast) {
    unsigned short* freN = xpad;  // region reused: freN dead after gemm1n; border zeroed in attn_all
    prep_kernel<<<dim3(29184), dim3(256), 0, stream>>>(
        rgb, fre, rgbN, freN,
        qv_w, qv_b, k_w, k_b, ng, nb, nm, nv, Wq, bq, Wk, bk,
        oc_w, oc_g, oc_b, oc_m, oc_v, Wc, soc, toc);
    gemm1n_all_kernel<<<dim3(5184), dim3(512), 0, stream>>>(rgbN, freN, Wq, bq, Wk, bk, qvbuf, kbuf);
    attn_all_kernel<<<dim3(7684), dim3(256), 0, stream>>>(qvbuf, kbuf, rgb, rgbN, xpad, 1);
    conv3d_kernel<<<dim3(1728), dim3(512), 0, stream>>>(xpad, Wc, soc, toc, out);
  } else {
    fold_qvk_kernel<<<dim3(1152), dim3(128), 0, stream>>>(qv_w, qv_b, k_w, k_b, ng, nb, nm, nv, Wq, bq, Wk, bk);
    fold_oc_kernel<<<dim3(384), dim3(256), 0, stream>>>(oc_w, oc_g, oc_b, oc_m, oc_v, Wc, soc, toc);
    gemm1_kernel<<<dim3(4 * 288 * 6), dim3(256), 0, stream>>>(rgb, Wq, bq, qvbuf, 768, 6);
    gemm1_kernel<<<dim3(4 * 288 * 3), dim3(256), 0, stream>>>(fre, Wk, bk, kbuf, 384, 3);
    attn_all_kernel<<<dim3(6912), dim3(256), 0, stream>>>(qvbuf, kbuf, rgb, qvbuf, qvbuf, 0);
    conv3_kernel<<<dim3(4 * 3 * 288), dim3(256), 0, stream>>>(qvbuf, Wc, soc, toc, out);
  }
}